// Round 4
// baseline (428.453 us; speedup 1.0000x reference)
//
#include <hip/hip_runtime.h>
#include <hip/hip_bf16.h>
#include <stdint.h>

typedef unsigned short u16;
typedef u16 u16x8 __attribute__((ext_vector_type(8)));
typedef u16x8 __attribute__((may_alias)) u16x8a;
typedef float f32x4 __attribute__((ext_vector_type(4)));
typedef f32x4 __attribute__((may_alias)) f32x4a;
typedef __bf16 bf16x8 __attribute__((ext_vector_type(8)));
typedef float f32x16 __attribute__((ext_vector_type(16)));

#define S_LEN 1024
#define D_DIM 64
#define BHN   64

__device__ __forceinline__ u16 f2bf(float f) {  // RNE float->bf16 (finite inputs)
  unsigned u = __builtin_bit_cast(unsigned, f);
  return (u16)((u + 0x7fffu + ((u >> 16) & 1u)) >> 16);
}
__device__ __forceinline__ float bf2f(u16 b) {
  return __builtin_bit_cast(float, (unsigned)b << 16);
}
// load 8 consecutive fp32 from global, round to bf16x8 fragment
__device__ __forceinline__ bf16x8 cvt8(const float* p) {
  f32x4 a = *reinterpret_cast<const f32x4a*>(p);
  f32x4 b = *reinterpret_cast<const f32x4a*>(p + 4);
  u16x8 r;
#pragma unroll
  for (int j = 0; j < 4; ++j) { r[j] = f2bf(a[j]); r[4 + j] = f2bf(b[j]); }
  return __builtin_bit_cast(bf16x8, r);
}
__device__ __forceinline__ bf16x8 ldbf(const u16* p) {
  return __builtin_bit_cast(bf16x8, *reinterpret_cast<const u16x8a*>(p));
}

// ---------------- fused attention (fp32 in / fp32 out, bf16 MFMA inside) -------------
// block: 256 thr = 4 waves, one (bh, 32-row q tile). wave w owns k-cols [256w,256w+256).
// LDS: ping-pong P-bounce tiles [2][4][32][40] u16 (20480 B) aliased under
// O-reduce [4][32][68] f32 (34816 B), + rowsum [4][32] f32 + inv [32] f32.
#define SMEM_BYTES 35456
#define RS_OFF     34816
#define INV_OFF    (34816 + 512)

__global__ __launch_bounds__(256, 3) void attn_kernel(
    const float* __restrict__ Q, const float* __restrict__ K, const int* __restrict__ Mk,
    const float* __restrict__ V, float* __restrict__ outO, float* __restrict__ outA) {
  __shared__ __align__(16) char smem[SMEM_BYTES];
  const int tid = threadIdx.x;
  const int wave = tid >> 6, lane = tid & 63;
  const int l31 = lane & 31, half = lane >> 5;

  // XCD swizzle: all 32 q-tiles of a bh land on one XCD (K/V L2 reuse).
  const int id = blockIdx.x;                  // 0..2047
  const int bh = (id & 7) * 8 + ((id >> 3) & 7);
  const int q0 = (id >> 6) << 5;              // q-tile * 32

  u16* tbase = (u16*)smem;                    // ping-pong bounce tiles
  float* rs_lds = (float*)(smem + RS_OFF);    // [4][32]
  float* inv_lds = (float*)(smem + INV_OFF);  // [32]

  // ---- Q A-fragments: lane holds Q[q0+l31][ks*16 + half*8 + j] (fp32 -> bf16) ----
  const float* qb = Q + (((size_t)bh << 10) + q0 + l31) * D_DIM + half * 8;
  bf16x8 qa[4];
#pragma unroll
  for (int ks = 0; ks < 4; ++ks) qa[ks] = cvt8(qb + ks * 16);

  const int colbase = wave * 256;
  const float* kb0 = K + ((size_t)bh << 10) * D_DIM + half * 8;
  const int* mrow = Mk + ((size_t)bh << 10) + colbase + l31;

  bf16x8 pfrag[16];  // wave's unnormalized exp(P) chunk [32 x 256] as A-frags
  float rs[16];
#pragma unroll
  for (int r = 0; r < 16; ++r) rs[r] = 0.0f;

  // ---- phase 1: QK^T -> exp -> A-layout frags (ping-pong bounce, barrier-fenced) ----
#pragma unroll
  for (int t = 0; t < 8; ++t) {
    u16* tile = tbase + (((t & 1) << 2) + wave) * (32 * 40);
    const int col0 = colbase + t * 32;
    const float* kb = kb0 + (size_t)(col0 + l31) * D_DIM;
    f32x16 acc = 0.0f;
#pragma unroll
    for (int ks = 0; ks < 4; ++ks) {
      bf16x8 kf = cvt8(kb + ks * 16);
      acc = __builtin_amdgcn_mfma_f32_32x32x16_bf16(qa[ks], kf, acc, 0, 0, 0);
    }
    const float mf = (mrow[t * 32] == 0) ? 0.0f : 1.0f;
#pragma unroll
    for (int r = 0; r < 16; ++r) {
      // score = acc/8 ; exp(score) = exp2(acc * 0.125*log2(e)); no max-sub needed
      float p = exp2f(acc[r] * 0.18033688f) * mf;
      u16 pb16 = f2bf(p);
      rs[r] += bf2f(pb16);  // bf16-consistent numerator/denominator
      const int row = (r & 3) + ((r >> 2) << 3) + (half << 2);  // C-layout row
      tile[row * 40 + l31] = pb16;
    }
    __syncthreads();  // fence: bounce write -> bounce read (WAR handled by ping-pong)
    pfrag[2 * t]     = ldbf(tile + l31 * 40 + half * 8);
    pfrag[2 * t + 1] = ldbf(tile + l31 * 40 + 16 + half * 8);
  }

  // ---- row sums: butterfly within 32-lane half, then cross-wave via LDS ----
#pragma unroll
  for (int r = 0; r < 16; ++r) {
    float s = rs[r];
#pragma unroll
    for (int m = 1; m < 32; m <<= 1) s += __shfl_xor(s, m, 64);
    rs[r] = s;
  }
  if (l31 == 0) {
#pragma unroll
    for (int r = 0; r < 16; ++r) {
      const int row = (r & 3) + ((r >> 2) << 3) + (half << 2);
      rs_lds[wave * 32 + row] = rs[r];
    }
  }
  __syncthreads();
  if (tid < 32) {
    float s = rs_lds[tid] + rs_lds[32 + tid] + rs_lds[64 + tid] + rs_lds[96 + tid];
    inv_lds[tid] = 1.0f / s;
  }
  __syncthreads();

  // ---- PV: O_partial[32x64]; B-frags scalar-loaded straight from global V ----
  // b0[j] = bf16(V[colbase + kk*16 + half*8 + j][l31]); b1: d = 32+l31
  f32x16 oacc0 = 0.0f, oacc1 = 0.0f;
  const float* vb = V + (((size_t)bh << 10) + colbase + half * 8) * D_DIM + l31;
#pragma unroll
  for (int kk = 0; kk < 16; ++kk) {
    u16x8 b0u, b1u;
#pragma unroll
    for (int j = 0; j < 8; ++j) {
      b0u[j] = f2bf(vb[(kk * 16 + j) * D_DIM]);
      b1u[j] = f2bf(vb[(kk * 16 + j) * D_DIM + 32]);
    }
    bf16x8 b0 = __builtin_bit_cast(bf16x8, b0u);
    bf16x8 b1 = __builtin_bit_cast(bf16x8, b1u);
    oacc0 = __builtin_amdgcn_mfma_f32_32x32x16_bf16(pfrag[kk], b0, oacc0, 0, 0, 0);
    oacc1 = __builtin_amdgcn_mfma_f32_32x32x16_bf16(pfrag[kk], b1, oacc1, 0, 0, 0);
  }

  // ---- attn write (fp32): direct from A-layout registers, 32B/lane runs ----
  const float myinv = inv_lds[l31];
  float* ab = outA + ((size_t)bh << 20) + ((size_t)(q0 + l31) << 10) + colbase + half * 8;
#pragma unroll
  for (int t = 0; t < 8; ++t) {
#pragma unroll
    for (int f = 0; f < 2; ++f) {
      bf16x8 pf = pfrag[2 * t + f];
      f32x4 lo, hi;
#pragma unroll
      for (int j = 0; j < 4; ++j) {
        lo[j] = (float)pf[j] * myinv;
        hi[j] = (float)pf[4 + j] * myinv;
      }
      *reinterpret_cast<f32x4a*>(ab + t * 32 + f * 16) = lo;
      *reinterpret_cast<f32x4a*>(ab + t * 32 + f * 16 + 4) = hi;
    }
  }

  // ---- cross-wave O reduction (LDS aliased over the bounce tiles) ----
  float* ored = (float*)smem;  // [4][32][68]
#pragma unroll
  for (int r = 0; r < 16; ++r) {
    const int row = (r & 3) + ((r >> 2) << 3) + (half << 2);
    ored[(wave * 32 + row) * 68 + l31] = oacc0[r];
    ored[(wave * 32 + row) * 68 + 32 + l31] = oacc1[r];
  }
  __syncthreads();
  const int orow = tid >> 3;
  const int oc = (tid & 7) * 8;
  const float iv = inv_lds[orow];
  f32x4 o0, o1;
#pragma unroll
  for (int j = 0; j < 8; ++j) {
    float o = ored[orow * 68 + oc + j] + ored[(32 + orow) * 68 + oc + j] +
              ored[(64 + orow) * 68 + oc + j] + ored[(96 + orow) * 68 + oc + j];
    float v = o * iv;
    if (j < 4) o0[j] = v; else o1[j - 4] = v;
  }
  float* ob = outO + (((size_t)bh << 10) + q0 + orow) * D_DIM + oc;
  *reinterpret_cast<f32x4a*>(ob) = o0;
  *reinterpret_cast<f32x4a*>(ob + 4) = o1;
}

extern "C" void kernel_launch(void* const* d_in, const int* in_sizes, int n_in,
                              void* d_out, int out_size, void* d_ws, size_t ws_size,
                              hipStream_t stream) {
  (void)in_sizes; (void)n_in; (void)out_size; (void)d_ws; (void)ws_size;
  const float* Q = (const float*)d_in[0];
  const float* K = (const float*)d_in[1];
  const float* V = (const float*)d_in[2];
  const int*   M = (const int*)d_in[3];
  float* outO = (float*)d_out;
  float* outA = outO + (size_t)BHN * S_LEN * D_DIM;  // attn follows output, flat

  attn_kernel<<<dim3(BHN * (S_LEN / 32)), dim3(256), 0, stream>>>(Q, K, M, V, outO, outA);
}